// Round 2
// baseline (7374.081 us; speedup 1.0000x reference)
//
#include <hip/hip_runtime.h>
#include <hip/hip_bf16.h>

typedef unsigned short u16;
typedef unsigned int   u32;

#define N_NODES 50000
#define N_EDGES 800000

// ---- ws layout (float offsets) ----
#define OFF_SPRE 0
#define OFF_VPRE 800000
#define OFF_AS   3200000
#define OFF_AV   4800000
#define OFF_WBUF 12000000
// wbuf internal offsets (floats)
#define WB_W1T  0      // [64][8]  w1t[j*8+i] = W1[i][j]
#define WB_B1   512
#define WB_W2T  576    // [80][64] w2t[o*64+j] = W2[j][o]
#define WB_WINS 5696   // [16][16]
#define WB_WINV 5952   // [16][16]
#define WB_WOS  6208   // [32][32]
#define WB_WOV  7232   // [48][16]
#define WB_SCS  8000   // [4][16][32]
#define WB_SCV  10048  // [4][16][16]
#define WB_FLAG 11072  // int flag: 1 => inputs are float32, 0 => bf16

__device__ __forceinline__ float bf2f(u16 v){
  union { u32 u; float f; } x; x.u = ((u32)v) << 16; return x.f;
}
__device__ __forceinline__ u16 f2bf(float f){
  u32 u = __float_as_uint(f);
  u32 lsb = (u >> 16) & 1u;
  u32 r = u + 0x7fffu + lsb;   // round-to-nearest-even
  return (u16)(r >> 16);
}
// dtype-flexible scalar load
__device__ __forceinline__ float ldx(const void* p, int i, int isf){
  return isf ? ((const float*)p)[i] : bf2f(((const u16*)p)[i]);
}
__device__ __forceinline__ float sigmoidf_(float x){ return 1.f/(1.f + __expf(-x)); }

// radial_emb is uniform[0,1). If bf16: every 16-bit half has sign==0 and exp<=126.
// If f32: low halves are random mantissa bits -> fails almost surely.
__global__ void detect_dtype(const u32* __restrict__ remb_raw, int* __restrict__ flag){
  int isf32 = 0;
  for (int k = 0; k < 64; k++){
    u32 w = remb_raw[k];
    u32 lo = w & 0xffffu, hi = w >> 16;
    int okl = ((lo & 0x8000u) == 0) && (((lo >> 7) & 0xffu) <= 126u);
    int okh = ((hi & 0x8000u) == 0) && (((hi >> 7) & 0xffu) <= 126u);
    if (!(okl && okh)) isf32 = 1;
  }
  *flag = isf32;
}

__global__ void prep_weights(const void* __restrict__ w1, const void* __restrict__ b1g,
                             const void* __restrict__ w2, const void* __restrict__ wins,
                             const void* __restrict__ winv, const void* __restrict__ wos,
                             const void* __restrict__ wov, const void* __restrict__ scs,
                             const void* __restrict__ scv, float* __restrict__ wbuf,
                             const int* __restrict__ flag){
  int t = threadIdx.x;
  int isf = *flag;
  for (int idx=t; idx<512;  idx+=256){ int j=idx>>3, i=idx&7;  wbuf[WB_W1T+idx] = ldx(w1, i*64+j, isf); }
  for (int idx=t; idx<64;   idx+=256){ wbuf[WB_B1+idx]  = ldx(b1g, idx, isf); }
  for (int idx=t; idx<5120; idx+=256){ int o=idx>>6, j=idx&63; wbuf[WB_W2T+idx] = ldx(w2, j*80+o, isf); }
  for (int idx=t; idx<256;  idx+=256){ wbuf[WB_WINS+idx] = ldx(wins, idx, isf); }
  for (int idx=t; idx<256;  idx+=256){ wbuf[WB_WINV+idx] = ldx(winv, idx, isf); }
  for (int idx=t; idx<1024; idx+=256){ wbuf[WB_WOS+idx]  = ldx(wos, idx, isf); }
  for (int idx=t; idx<768;  idx+=256){ wbuf[WB_WOV+idx]  = ldx(wov, idx, isf); }
  for (int idx=t; idx<2048; idx+=256){ wbuf[WB_SCS+idx]  = ldx(scs, idx, isf); }
  for (int idx=t; idx<1024; idx+=256){ wbuf[WB_SCV+idx]  = ldx(scv, idx, isf); }
}

__global__ void node_pre(const void* __restrict__ ns_g, const void* __restrict__ nv_g,
                         const float* __restrict__ wbuf, float* __restrict__ s_pre,
                         float* __restrict__ v_pre, const int* __restrict__ flag){
  int n = blockIdx.x*256 + threadIdx.x;
  if (n >= N_NODES) return;
  int isf = *flag;
  float a[16], b[48];
  #pragma unroll
  for (int u=0;u<16;u++) a[u] = ldx(ns_g, n*16+u, isf);
  #pragma unroll
  for (int u=0;u<48;u++) b[u] = ldx(nv_g, n*48+u, isf);

  const float* wins = wbuf + WB_WINS;
  const float* winv = wbuf + WB_WINV;
  float s[16];
  #pragma unroll
  for (int w=0;w<16;w++) s[w]=0.f;
  #pragma unroll
  for (int u=0;u<16;u++){
    float au = a[u];
    #pragma unroll
    for (int w=0;w<16;w++) s[w] += au * wins[u*16+w];
  }
  float* sp = s_pre + n*16;
  #pragma unroll
  for (int w=0;w<16;w++) sp[w] = s[w];
  float v0[16], v1[16], v2[16];
  #pragma unroll
  for (int w=0;w<16;w++){ v0[w]=0.f; v1[w]=0.f; v2[w]=0.f; }
  #pragma unroll
  for (int u=0;u<16;u++){
    float bu0=b[u*3], bu1=b[u*3+1], bu2=b[u*3+2];
    #pragma unroll
    for (int w=0;w<16;w++){
      float wv = winv[u*16+w];
      v0[w] += bu0*wv; v1[w] += bu1*wv; v2[w] += bu2*wv;
    }
  }
  float* vp = v_pre + n*48;
  #pragma unroll
  for (int w=0;w<16;w++){ vp[w*3]=v0[w]; vp[w*3+1]=v1[w]; vp[w*3+2]=v2[w]; }
}

__global__ void __launch_bounds__(256) edge_kernel(
    const void* __restrict__ edge_sh, const void* __restrict__ remb,
    const int* __restrict__ senders, const int* __restrict__ receivers,
    const float* __restrict__ s_pre, const float* __restrict__ v_pre,
    const float* __restrict__ wbuf, float* __restrict__ a_s, float* __restrict__ a_v,
    const int* __restrict__ flag){
  int e = blockIdx.x*256 + threadIdx.x;
  if (e >= N_EDGES) return;
  int isf = *flag;
  float Y0  = ldx(edge_sh, e*4+0, isf);
  float Yv0 = ldx(edge_sh, e*4+1, isf);
  float Yv1 = ldx(edge_sh, e*4+2, isf);
  float Yv2 = ldx(edge_sh, e*4+3, isf);
  float re[8];
  #pragma unroll
  for (int i=0;i<8;i++) re[i] = ldx(remb, e*8+i, isf);
  int snd = senders[e], rcv = receivers[e];

  const float* w1t = wbuf + WB_W1T;
  const float* b1  = wbuf + WB_B1;
  const float* w2t = wbuf + WB_W2T;

  float h[64];
  #pragma unroll
  for (int j=0;j<64;j++){
    float acc = b1[j];
    #pragma unroll
    for (int i=0;i<8;i++) acc += re[i] * w1t[j*8+i];
    h[j] = acc * sigmoidf_(acc);          // silu
  }

  const float* srow = s_pre + snd*16;
  const float* vrow = v_pre + snd*48;
  float* asr = a_s + rcv*32;
  float* avr = a_v + rcv*144;

  for (int u0=0; u0<16; u0+=4){
    float4 xsq = *reinterpret_cast<const float4*>(srow + u0);
    float4 xa  = *reinterpret_cast<const float4*>(vrow + u0*3);
    float4 xb  = *reinterpret_cast<const float4*>(vrow + u0*3 + 4);
    float4 xc  = *reinterpret_cast<const float4*>(vrow + u0*3 + 8);
    float xs_[4]  = {xsq.x, xsq.y, xsq.z, xsq.w};
    float xv_[12] = {xa.x,xa.y,xa.z,xa.w, xb.x,xb.y,xb.z,xb.w, xc.x,xc.y,xc.z,xc.w};
    #pragma unroll
    for (int k=0;k<4;k++){
      const float* wp = w2t + (u0+k)*64;  // wave-uniform address
      float w0=0.f,w1=0.f,w2=0.f,w3=0.f,w4=0.f;
      #pragma unroll
      for (int j=0;j<64;j++){
        float hj = h[j];
        w0 += hj*wp[j];
        w1 += hj*wp[1024 + j];
        w2 += hj*wp[2048 + j];
        w3 += hj*wp[3072 + j];
        w4 += hj*wp[4096 + j];
      }
      float xs = xs_[k];
      float x0 = xv_[k*3], x1 = xv_[k*3+1], x2 = xv_[k*3+2];
      int u = u0 + k;
      unsafeAtomicAdd(asr + u,       w0 * xs * Y0);
      unsafeAtomicAdd(asr + 16 + u,  w1 * (x0*Yv0 + x1*Yv1 + x2*Yv2));
      float t1 = w2 * xs;
      unsafeAtomicAdd(avr + u,       t1 * Yv0);
      unsafeAtomicAdd(avr + 48 + u,  t1 * Yv1);
      unsafeAtomicAdd(avr + 96 + u,  t1 * Yv2);
      float t2 = w3 * Y0;
      unsafeAtomicAdd(avr + 16 + u,  t2 * x0);
      unsafeAtomicAdd(avr + 64 + u,  t2 * x1);
      unsafeAtomicAdd(avr + 112 + u, t2 * x2);
      unsafeAtomicAdd(avr + 32 + u,  w4 * (x1*Yv2 - x2*Yv1));
      unsafeAtomicAdd(avr + 80 + u,  w4 * (x2*Yv0 - x0*Yv2));
      unsafeAtomicAdd(avr + 128 + u, w4 * (x0*Yv1 - x1*Yv0));
    }
  }
}

__global__ void node_post(const void* __restrict__ ns_g, const void* __restrict__ nv_g,
                          const int* __restrict__ species, const float* __restrict__ wbuf,
                          const float* __restrict__ a_s, const float* __restrict__ a_v,
                          void* __restrict__ out, const int* __restrict__ flag){
  int n = blockIdx.x*256 + threadIdx.x;
  if (n >= N_NODES) return;
  int isf = *flag;
  int sp = species[n];
  float ns[16], vin[48];
  #pragma unroll
  for (int u=0;u<16;u++) ns[u] = ldx(ns_g, n*16+u, isf);
  #pragma unroll
  for (int u=0;u<48;u++) vin[u] = ldx(nv_g, n*48+u, isf);

  const float* wos = wbuf + WB_WOS;
  const float* wov = wbuf + WB_WOV;
  const float* scs = wbuf + WB_SCS + sp*512;
  const float* scv = wbuf + WB_SCV + sp*256;
  const float* ar  = a_s + n*32;

  float ps[32];
  #pragma unroll
  for (int w=0;w<32;w++) ps[w]=0.f;
  for (int u=0;u<32;u++){
    float au = ar[u]*0.25f;               // inv_sqrt_deg = 1/sqrt(16)
    #pragma unroll
    for (int w=0;w<32;w++) ps[w] += au*wos[u*32+w];
  }
  #pragma unroll
  for (int u=0;u<16;u++){
    float nu = ns[u];
    #pragma unroll
    for (int w=0;w<32;w++) ps[w] += nu*scs[u*32+w];
  }
  float ores[64];
  float gate[16];
  #pragma unroll
  for (int k=0;k<16;k++){
    float x = ps[k];
    ores[k] = x * sigmoidf_(x) + ns[k];
    gate[k] = sigmoidf_(ps[16+k]);
  }
  for (int c=0;c<3;c++){
    const float* avc = a_v + n*144 + c*48;
    float pv[16];
    #pragma unroll
    for (int w=0;w<16;w++) pv[w]=0.f;
    for (int u=0;u<48;u++){
      float au = avc[u]*0.25f;
      #pragma unroll
      for (int w=0;w<16;w++) pv[w] += au*wov[u*16+w];
    }
    #pragma unroll
    for (int u=0;u<16;u++){
      float bu = vin[u*3+c];
      #pragma unroll
      for (int w=0;w<16;w++) pv[w] += bu*scv[u*16+w];
    }
    #pragma unroll
    for (int w=0;w<16;w++)
      ores[16 + w*3 + c] = pv[w]*gate[w] + vin[w*3+c];
  }
  if (isf){
    float* orow = (float*)out + n*64;
    #pragma unroll
    for (int k=0;k<64;k++) orow[k] = ores[k];
  } else {
    u16* orow = (u16*)out + n*64;
    #pragma unroll
    for (int k=0;k<64;k++) orow[k] = f2bf(ores[k]);
  }
}

extern "C" void kernel_launch(void* const* d_in, const int* in_sizes, int n_in,
                              void* d_out, int out_size, void* d_ws, size_t ws_size,
                              hipStream_t stream){
  const void* node_scalars = d_in[0];
  const void* node_vectors = d_in[1];
  const void* edge_sh      = d_in[2];
  const void* radial_emb   = d_in[3];
  const int* senders      = (const int*)d_in[4];
  const int* receivers    = (const int*)d_in[5];
  const int* species      = (const int*)d_in[6];
  const void* W_in_s  = d_in[7];
  const void* W_in_v  = d_in[8];
  const void* mlp_w1  = d_in[9];
  const void* mlp_b1  = d_in[10];
  const void* mlp_w2  = d_in[11];
  const void* W_out_s = d_in[12];
  const void* W_out_v = d_in[13];
  const void* sc_s    = d_in[14];
  const void* sc_v    = d_in[15];

  float* ws    = (float*)d_ws;
  float* s_pre = ws + OFF_SPRE;
  float* v_pre = ws + OFF_VPRE;
  float* a_s   = ws + OFF_AS;
  float* a_v   = ws + OFF_AV;
  float* wbuf  = ws + OFF_WBUF;
  int*   flag  = (int*)(wbuf + WB_FLAG);

  detect_dtype<<<1,1,0,stream>>>((const u32*)radial_emb, flag);
  hipMemsetAsync(a_s, 0, (size_t)(1600000 + 7200000)*sizeof(float), stream);
  prep_weights<<<1,256,0,stream>>>(mlp_w1, mlp_b1, mlp_w2, W_in_s, W_in_v,
                                   W_out_s, W_out_v, sc_s, sc_v, wbuf, flag);
  node_pre<<<(N_NODES+255)/256,256,0,stream>>>(node_scalars, node_vectors, wbuf, s_pre, v_pre, flag);
  edge_kernel<<<N_EDGES/256,256,0,stream>>>(edge_sh, radial_emb, senders, receivers,
                                            s_pre, v_pre, wbuf, a_s, a_v, flag);
  node_post<<<(N_NODES+255)/256,256,0,stream>>>(node_scalars, node_vectors, species,
                                                wbuf, a_s, a_v, d_out, flag);
}

// Round 3
// 2263.856 us; speedup vs baseline: 3.2573x; 3.2573x over previous
//
#include <hip/hip_runtime.h>
#include <hip/hip_bf16.h>

typedef unsigned short u16;
typedef unsigned int   u32;

#define N_NODES 50000
#define N_EDGES 800000

// ---- ws layout (4-byte units) ----
#define OFF_AS    0          // a_s: 50000*32 f32 = 1,600,000
#define OFF_AV    1600000    // a_v: 50000*144 f32 = 7,200,000
#define OFF_WBUF  8800000    // 11,073 f32
#define OFF_SP16  8812000    // s_pre bf16: 800,000 u16 (400,000 slots)
#define OFF_VP16  9212000    // v_pre bf16: 2,400,000 u16 (1,200,000 slots)
#define IDX_DEG   10412000   // 50,000 int
#define IDX_OFFS  10470000   // 50,001 int
#define IDX_CURS  10530000   // 50,000 int
#define IDX_BUCK  10590000   // 800,000 int  -> ends 11,390,000 (45.6 MB)

// wbuf internal offsets (floats)
#define WB_W1T  0      // [64][8]  w1t[j*8+i] = W1[i][j]
#define WB_B1   512
#define WB_W2T  576    // [80][64] w2t[o*64+j] = W2[j][o], o = path*16+u
#define WB_WINS 5696
#define WB_WINV 5952
#define WB_WOS  6208
#define WB_WOV  7232
#define WB_SCS  8000
#define WB_SCV  10048
#define WB_FLAG 11072

__device__ __forceinline__ float bf2f(u16 v){
  union { u32 u; float f; } x; x.u = ((u32)v) << 16; return x.f;
}
__device__ __forceinline__ u16 f2bf(float f){
  u32 u = __float_as_uint(f);
  u32 lsb = (u >> 16) & 1u;
  u32 r = u + 0x7fffu + lsb;
  return (u16)(r >> 16);
}
__device__ __forceinline__ float ldx(const void* p, int i, int isf){
  return isf ? ((const float*)p)[i] : bf2f(((const u16*)p)[i]);
}
__device__ __forceinline__ void unpack8(uint4 q, float* d){
  d[0]=bf2f((u16)(q.x&0xffffu)); d[1]=bf2f((u16)(q.x>>16));
  d[2]=bf2f((u16)(q.y&0xffffu)); d[3]=bf2f((u16)(q.y>>16));
  d[4]=bf2f((u16)(q.z&0xffffu)); d[5]=bf2f((u16)(q.z>>16));
  d[6]=bf2f((u16)(q.w&0xffffu)); d[7]=bf2f((u16)(q.w>>16));
}
__device__ __forceinline__ float sigmoidf_(float x){ return 1.f/(1.f + __expf(-x)); }

__global__ void detect_dtype(const u32* __restrict__ remb_raw, int* __restrict__ flag){
  int isf32 = 0;
  for (int k = 0; k < 64; k++){
    u32 w = remb_raw[k];
    u32 lo = w & 0xffffu, hi = w >> 16;
    int okl = ((lo & 0x8000u) == 0) && (((lo >> 7) & 0xffu) <= 126u);
    int okh = ((hi & 0x8000u) == 0) && (((hi >> 7) & 0xffu) <= 126u);
    if (!(okl && okh)) isf32 = 1;
  }
  *flag = isf32;
}

__global__ void prep_weights(const void* __restrict__ w1, const void* __restrict__ b1g,
                             const void* __restrict__ w2, const void* __restrict__ wins,
                             const void* __restrict__ winv, const void* __restrict__ wos,
                             const void* __restrict__ wov, const void* __restrict__ scs,
                             const void* __restrict__ scv, float* __restrict__ wbuf,
                             const int* __restrict__ flag){
  int t = threadIdx.x;
  int isf = *flag;
  for (int idx=t; idx<512;  idx+=256){ int j=idx>>3, i=idx&7;  wbuf[WB_W1T+idx] = ldx(w1, i*64+j, isf); }
  for (int idx=t; idx<64;   idx+=256){ wbuf[WB_B1+idx]  = ldx(b1g, idx, isf); }
  for (int idx=t; idx<5120; idx+=256){ int o=idx>>6, j=idx&63; wbuf[WB_W2T+idx] = ldx(w2, j*80+o, isf); }
  for (int idx=t; idx<256;  idx+=256){ wbuf[WB_WINS+idx] = ldx(wins, idx, isf); }
  for (int idx=t; idx<256;  idx+=256){ wbuf[WB_WINV+idx] = ldx(winv, idx, isf); }
  for (int idx=t; idx<1024; idx+=256){ wbuf[WB_WOS+idx]  = ldx(wos, idx, isf); }
  for (int idx=t; idx<768;  idx+=256){ wbuf[WB_WOV+idx]  = ldx(wov, idx, isf); }
  for (int idx=t; idx<2048; idx+=256){ wbuf[WB_SCS+idx]  = ldx(scs, idx, isf); }
  for (int idx=t; idx<1024; idx+=256){ wbuf[WB_SCV+idx]  = ldx(scv, idx, isf); }
}

__global__ void node_pre(const void* __restrict__ ns_g, const void* __restrict__ nv_g,
                         const float* __restrict__ wbuf, u16* __restrict__ sp16,
                         u16* __restrict__ vp16, const int* __restrict__ flag){
  int n = blockIdx.x*256 + threadIdx.x;
  if (n >= N_NODES) return;
  int isf = *flag;
  float a[16], b[48];
  #pragma unroll
  for (int u=0;u<16;u++) a[u] = ldx(ns_g, n*16+u, isf);
  #pragma unroll
  for (int u=0;u<48;u++) b[u] = ldx(nv_g, n*48+u, isf);

  const float* wins = wbuf + WB_WINS;
  const float* winv = wbuf + WB_WINV;
  float s[16];
  #pragma unroll
  for (int w=0;w<16;w++) s[w]=0.f;
  #pragma unroll
  for (int u=0;u<16;u++){
    float au = a[u];
    #pragma unroll
    for (int w=0;w<16;w++) s[w] += au * wins[u*16+w];
  }
  #pragma unroll
  for (int w=0;w<16;w++) sp16[n*16+w] = f2bf(s[w]);
  float v0[16], v1[16], v2[16];
  #pragma unroll
  for (int w=0;w<16;w++){ v0[w]=0.f; v1[w]=0.f; v2[w]=0.f; }
  #pragma unroll
  for (int u=0;u<16;u++){
    float bu0=b[u*3], bu1=b[u*3+1], bu2=b[u*3+2];
    #pragma unroll
    for (int w=0;w<16;w++){
      float wv = winv[u*16+w];
      v0[w] += bu0*wv; v1[w] += bu1*wv; v2[w] += bu2*wv;
    }
  }
  #pragma unroll
  for (int w=0;w<16;w++){
    vp16[n*48+w*3]   = f2bf(v0[w]);
    vp16[n*48+w*3+1] = f2bf(v1[w]);
    vp16[n*48+w*3+2] = f2bf(v2[w]);
  }
}

__global__ void count_edges(const int* __restrict__ receivers, int* __restrict__ deg){
  int e = blockIdx.x*256 + threadIdx.x;
  if (e < N_EDGES) atomicAdd(&deg[receivers[e]], 1);
}

__global__ void scan_offsets(const int* __restrict__ deg, int* __restrict__ offs,
                             int* __restrict__ curs){
  __shared__ int part[1024];
  int t = threadIdx.x;
  const int PER = 49;                 // 1024*49 = 50176 >= 50000
  int base = t*PER;
  int s = 0;
  for (int i=0;i<PER;i++){ int n=base+i; if (n<N_NODES) s += deg[n]; }
  part[t] = s; __syncthreads();
  for (int off=1; off<1024; off<<=1){
    int v = (t>=off) ? part[t-off] : 0;
    __syncthreads(); part[t] += v; __syncthreads();
  }
  int run = (t==0) ? 0 : part[t-1];   // exclusive prefix
  for (int i=0;i<PER;i++){
    int n=base+i;
    if (n<N_NODES){ offs[n]=run; curs[n]=run; run += deg[n]; }
  }
  if (t==1023) offs[N_NODES] = run;
}

__global__ void fill_bucket(const int* __restrict__ receivers, int* __restrict__ curs,
                            int* __restrict__ bucket){
  int e = blockIdx.x*256 + threadIdx.x;
  if (e < N_EDGES){
    int p = atomicAdd(&curs[receivers[e]], 1);
    bucket[p] = e;
  }
}

__global__ void __launch_bounds__(256) gather_kernel(
    const void* __restrict__ edge_sh, const void* __restrict__ remb,
    const int* __restrict__ senders, const int* __restrict__ offs,
    const int* __restrict__ bucket, const u16* __restrict__ sp16,
    const u16* __restrict__ vp16, const float* __restrict__ wbuf,
    float* __restrict__ a_s, float* __restrict__ a_v, const int* __restrict__ flag){
  int node = blockIdx.x*256 + threadIdx.x;
  int u0 = blockIdx.y*4;              // wave-uniform u-chunk -> W2 rows via s_load
  if (node >= N_NODES) return;
  int isf = *flag;
  int beg = offs[node], end = offs[node+1];
  const float* w1t = wbuf + WB_W1T;
  const float* b1  = wbuf + WB_B1;
  const float* w2t = wbuf + WB_W2T;

  float as0[4] = {0,0,0,0}, as1[4] = {0,0,0,0};
  float av[3][3][4];
  #pragma unroll
  for (int p=0;p<3;p++)
    #pragma unroll
    for (int c=0;c<3;c++)
      #pragma unroll
      for (int k=0;k<4;k++) av[p][c][k]=0.f;

  for (int idx=beg; idx<end; idx++){
    int e = bucket[idx];
    int snd = senders[e];
    float Y0,Yv0,Yv1,Yv2, re[8];
    if (isf){
      float4 s4 = *reinterpret_cast<const float4*>((const float*)edge_sh + (size_t)e*4);
      Y0=s4.x; Yv0=s4.y; Yv1=s4.z; Yv2=s4.w;
      const float4* rp = reinterpret_cast<const float4*>((const float*)remb + (size_t)e*8);
      float4 r0=rp[0], r1=rp[1];
      re[0]=r0.x; re[1]=r0.y; re[2]=r0.z; re[3]=r0.w;
      re[4]=r1.x; re[5]=r1.y; re[6]=r1.z; re[7]=r1.w;
    } else {
      uint2 shq = *reinterpret_cast<const uint2*>((const u16*)edge_sh + (size_t)e*4);
      Y0 =bf2f((u16)(shq.x&0xffffu)); Yv0=bf2f((u16)(shq.x>>16));
      Yv1=bf2f((u16)(shq.y&0xffffu)); Yv2=bf2f((u16)(shq.y>>16));
      uint4 rq = *reinterpret_cast<const uint4*>((const u16*)remb + (size_t)e*8);
      unpack8(rq, re);
    }
    // radial MLP hidden layer (weights wave-uniform -> scalar loads)
    float h[64];
    #pragma unroll
    for (int j=0;j<64;j++){
      float acc = b1[j];
      #pragma unroll
      for (int i=0;i<8;i++) acc += re[i] * w1t[j*8+i];
      h[j] = acc * sigmoidf_(acc);
    }
    // sender features (bf16 tables)
    float xs[4], xv[12];
    {
      uint2 sq = *reinterpret_cast<const uint2*>(sp16 + (size_t)snd*16 + u0);
      xs[0]=bf2f((u16)(sq.x&0xffffu)); xs[1]=bf2f((u16)(sq.x>>16));
      xs[2]=bf2f((u16)(sq.y&0xffffu)); xs[3]=bf2f((u16)(sq.y>>16));
      const u16* vr = vp16 + (size_t)snd*48 + u0*3;
      uint2 q0 = *reinterpret_cast<const uint2*>(vr);
      uint2 q1 = *reinterpret_cast<const uint2*>(vr+4);
      uint2 q2 = *reinterpret_cast<const uint2*>(vr+8);
      xv[0]=bf2f((u16)(q0.x&0xffffu)); xv[1]=bf2f((u16)(q0.x>>16));
      xv[2]=bf2f((u16)(q0.y&0xffffu)); xv[3]=bf2f((u16)(q0.y>>16));
      xv[4]=bf2f((u16)(q1.x&0xffffu)); xv[5]=bf2f((u16)(q1.x>>16));
      xv[6]=bf2f((u16)(q1.y&0xffffu)); xv[7]=bf2f((u16)(q1.y>>16));
      xv[8]=bf2f((u16)(q2.x&0xffffu)); xv[9]=bf2f((u16)(q2.x>>16));
      xv[10]=bf2f((u16)(q2.y&0xffffu)); xv[11]=bf2f((u16)(q2.y>>16));
    }
    #pragma unroll
    for (int k=0;k<4;k++){
      const float* wp = w2t + (u0+k)*64;     // path p at +p*1024
      float w0=0.f,w1=0.f,w2=0.f,w3=0.f,w4=0.f;
      #pragma unroll
      for (int j=0;j<64;j++){
        float hj = h[j];
        w0 += hj*wp[j];
        w1 += hj*wp[1024+j];
        w2 += hj*wp[2048+j];
        w3 += hj*wp[3072+j];
        w4 += hj*wp[4096+j];
      }
      float xsk = xs[k];
      float x0 = xv[3*k], x1 = xv[3*k+1], x2 = xv[3*k+2];
      as0[k] += w0 * xsk * Y0;
      as1[k] += w1 * (x0*Yv0 + x1*Yv1 + x2*Yv2);
      float t1 = w2 * xsk;
      av[0][0][k] += t1*Yv0; av[0][1][k] += t1*Yv1; av[0][2][k] += t1*Yv2;
      float t2 = w3 * Y0;
      av[1][0][k] += t2*x0;  av[1][1][k] += t2*x1;  av[1][2][k] += t2*x2;
      av[2][0][k] += w4*(x1*Yv2 - x2*Yv1);
      av[2][1][k] += w4*(x2*Yv0 - x0*Yv2);
      av[2][2][k] += w4*(x0*Yv1 - x1*Yv0);
    }
  }
  float* asr = a_s + (size_t)node*32;
  *reinterpret_cast<float4*>(asr + u0)      = make_float4(as0[0],as0[1],as0[2],as0[3]);
  *reinterpret_cast<float4*>(asr + 16 + u0) = make_float4(as1[0],as1[1],as1[2],as1[3]);
  float* avr = a_v + (size_t)node*144;
  #pragma unroll
  for (int p=0;p<3;p++)
    #pragma unroll
    for (int c=0;c<3;c++)
      *reinterpret_cast<float4*>(avr + c*48 + p*16 + u0) =
          make_float4(av[p][c][0],av[p][c][1],av[p][c][2],av[p][c][3]);
}

__global__ void node_post(const void* __restrict__ ns_g, const void* __restrict__ nv_g,
                          const int* __restrict__ species, const float* __restrict__ wbuf,
                          const float* __restrict__ a_s, const float* __restrict__ a_v,
                          void* __restrict__ out, const int* __restrict__ flag){
  int n = blockIdx.x*256 + threadIdx.x;
  if (n >= N_NODES) return;
  int isf = *flag;
  int sp = species[n];
  float ns[16], vin[48];
  #pragma unroll
  for (int u=0;u<16;u++) ns[u] = ldx(ns_g, n*16+u, isf);
  #pragma unroll
  for (int u=0;u<48;u++) vin[u] = ldx(nv_g, n*48+u, isf);

  const float* wos = wbuf + WB_WOS;
  const float* wov = wbuf + WB_WOV;
  const float* scs = wbuf + WB_SCS + sp*512;
  const float* scv = wbuf + WB_SCV + sp*256;
  const float* ar  = a_s + (size_t)n*32;

  float ps[32];
  #pragma unroll
  for (int w=0;w<32;w++) ps[w]=0.f;
  for (int u=0;u<32;u++){
    float au = ar[u]*0.25f;
    #pragma unroll
    for (int w=0;w<32;w++) ps[w] += au*wos[u*32+w];
  }
  #pragma unroll
  for (int u=0;u<16;u++){
    float nu = ns[u];
    #pragma unroll
    for (int w=0;w<32;w++) ps[w] += nu*scs[u*32+w];
  }
  float ores[64];
  float gate[16];
  #pragma unroll
  for (int k=0;k<16;k++){
    float x = ps[k];
    ores[k] = x * sigmoidf_(x) + ns[k];
    gate[k] = sigmoidf_(ps[16+k]);
  }
  for (int c=0;c<3;c++){
    const float* avc = a_v + (size_t)n*144 + c*48;
    float pv[16];
    #pragma unroll
    for (int w=0;w<16;w++) pv[w]=0.f;
    for (int u=0;u<48;u++){
      float au = avc[u]*0.25f;
      #pragma unroll
      for (int w=0;w<16;w++) pv[w] += au*wov[u*16+w];
    }
    #pragma unroll
    for (int u=0;u<16;u++){
      float bu = vin[u*3+c];
      #pragma unroll
      for (int w=0;w<16;w++) pv[w] += bu*scv[u*16+w];
    }
    #pragma unroll
    for (int w=0;w<16;w++)
      ores[16 + w*3 + c] = pv[w]*gate[w] + vin[w*3+c];
  }
  if (isf){
    float* orow = (float*)out + (size_t)n*64;
    #pragma unroll
    for (int k=0;k<64;k++) orow[k] = ores[k];
  } else {
    u16* orow = (u16*)out + (size_t)n*64;
    #pragma unroll
    for (int k=0;k<64;k++) orow[k] = f2bf(ores[k]);
  }
}

extern "C" void kernel_launch(void* const* d_in, const int* in_sizes, int n_in,
                              void* d_out, int out_size, void* d_ws, size_t ws_size,
                              hipStream_t stream){
  const void* node_scalars = d_in[0];
  const void* node_vectors = d_in[1];
  const void* edge_sh      = d_in[2];
  const void* radial_emb   = d_in[3];
  const int* senders      = (const int*)d_in[4];
  const int* receivers    = (const int*)d_in[5];
  const int* species      = (const int*)d_in[6];
  const void* W_in_s  = d_in[7];
  const void* W_in_v  = d_in[8];
  const void* mlp_w1  = d_in[9];
  const void* mlp_b1  = d_in[10];
  const void* mlp_w2  = d_in[11];
  const void* W_out_s = d_in[12];
  const void* W_out_v = d_in[13];
  const void* sc_s    = d_in[14];
  const void* sc_v    = d_in[15];

  float* wsf  = (float*)d_ws;
  int*   wsi  = (int*)d_ws;
  float* a_s  = wsf + OFF_AS;
  float* a_v  = wsf + OFF_AV;
  float* wbuf = wsf + OFF_WBUF;
  u16*   sp16 = (u16*)(wsf + OFF_SP16);
  u16*   vp16 = (u16*)(wsf + OFF_VP16);
  int*   deg  = wsi + IDX_DEG;
  int*   offs = wsi + IDX_OFFS;
  int*   curs = wsi + IDX_CURS;
  int*   buck = wsi + IDX_BUCK;
  int*   flag = (int*)(wbuf + WB_FLAG);

  detect_dtype<<<1,1,0,stream>>>((const u32*)radial_emb, flag);
  hipMemsetAsync(deg, 0, (size_t)N_NODES*sizeof(int), stream);
  prep_weights<<<1,256,0,stream>>>(mlp_w1, mlp_b1, mlp_w2, W_in_s, W_in_v,
                                   W_out_s, W_out_v, sc_s, sc_v, wbuf, flag);
  node_pre<<<(N_NODES+255)/256,256,0,stream>>>(node_scalars, node_vectors, wbuf,
                                               sp16, vp16, flag);
  count_edges<<<(N_EDGES+255)/256,256,0,stream>>>(receivers, deg);
  scan_offsets<<<1,1024,0,stream>>>(deg, offs, curs);
  fill_bucket<<<(N_EDGES+255)/256,256,0,stream>>>(receivers, curs, buck);
  gather_kernel<<<dim3((N_NODES+255)/256,4),256,0,stream>>>(
      edge_sh, radial_emb, senders, offs, buck, sp16, vp16, wbuf, a_s, a_v, flag);
  node_post<<<(N_NODES+255)/256,256,0,stream>>>(node_scalars, node_vectors, species,
                                                wbuf, a_s, a_v, d_out, flag);
}

// Round 4
// 2012.769 us; speedup vs baseline: 3.6637x; 1.1247x over previous
//
#include <hip/hip_runtime.h>
#include <hip/hip_bf16.h>

typedef unsigned short u16;
typedef unsigned int   u32;

#define N_NODES 50000
#define N_EDGES 800000

// ---- ws layout (u32/float units) ----
#define OFF_WBUF  0          // 11,073 floats
#define OFF_SP16  11080      // 800,000 u16 = 400,000 u32
#define OFF_VP16  411080     // 2,400,000 u16 = 1,200,000 u32
#define IDX_DEG   1611080    // 50,000 int
#define IDX_OFFS  1661080    // 50,001 int
#define IDX_CURS  1711088    // 50,000 int
#define IDX_PERM  1761088    // 800,000 records x 8 u32 = 6,400,000 -> ends 8,161,088 (32.6 MB)

// wbuf internal offsets (floats)
#define WB_W1T  0      // [64][8]  w1t[j*8+i] = W1[i][j]
#define WB_B1   512
#define WB_W2T  576    // [80][64] w2t[o*64+j] = W2[j][o], o = path*16+u
#define WB_WINS 5696
#define WB_WINV 5952
#define WB_WOS  6208
#define WB_WOV  7232
#define WB_SCS  8000
#define WB_SCV  10048
#define WB_FLAG 11072

#define RPB  64     // receivers per block in fused_gather
#define BINW 177    // 176 accum + 1 pad (bank spread)

__device__ __forceinline__ float bf2f(u16 v){
  union { u32 u; float f; } x; x.u = ((u32)v) << 16; return x.f;
}
__device__ __forceinline__ u16 f2bf(float f){
  u32 u = __float_as_uint(f);
  u32 lsb = (u >> 16) & 1u;
  u32 r = u + 0x7fffu + lsb;
  return (u16)(r >> 16);
}
__device__ __forceinline__ float ldx(const void* p, long long i, int isf){
  return isf ? ((const float*)p)[i] : bf2f(((const u16*)p)[i]);
}
__device__ __forceinline__ u32 pk2(float a, float b){
  return (u32)f2bf(a) | ((u32)f2bf(b) << 16);
}
__device__ __forceinline__ float sigmoidf_(float x){ return 1.f/(1.f + __expf(-x)); }

__global__ void detect_dtype(const u32* __restrict__ remb_raw, int* __restrict__ flag){
  int isf32 = 0;
  for (int k = 0; k < 64; k++){
    u32 w = remb_raw[k];
    u32 lo = w & 0xffffu, hi = w >> 16;
    int okl = ((lo & 0x8000u) == 0) && (((lo >> 7) & 0xffu) <= 126u);
    int okh = ((hi & 0x8000u) == 0) && (((hi >> 7) & 0xffu) <= 126u);
    if (!(okl && okh)) isf32 = 1;
  }
  *flag = isf32;
}

__global__ void prep_weights(const void* __restrict__ w1, const void* __restrict__ b1g,
                             const void* __restrict__ w2, const void* __restrict__ wins,
                             const void* __restrict__ winv, const void* __restrict__ wos,
                             const void* __restrict__ wov, const void* __restrict__ scs,
                             const void* __restrict__ scv, float* __restrict__ wbuf,
                             const int* __restrict__ flag){
  int t = threadIdx.x;
  int isf = *flag;
  for (int idx=t; idx<512;  idx+=256){ int j=idx>>3, i=idx&7;  wbuf[WB_W1T+idx] = ldx(w1, i*64+j, isf); }
  for (int idx=t; idx<64;   idx+=256){ wbuf[WB_B1+idx]  = ldx(b1g, idx, isf); }
  for (int idx=t; idx<5120; idx+=256){ int o=idx>>6, j=idx&63; wbuf[WB_W2T+idx] = ldx(w2, j*80+o, isf); }
  for (int idx=t; idx<256;  idx+=256){ wbuf[WB_WINS+idx] = ldx(wins, idx, isf); }
  for (int idx=t; idx<256;  idx+=256){ wbuf[WB_WINV+idx] = ldx(winv, idx, isf); }
  for (int idx=t; idx<1024; idx+=256){ wbuf[WB_WOS+idx]  = ldx(wos, idx, isf); }
  for (int idx=t; idx<768;  idx+=256){ wbuf[WB_WOV+idx]  = ldx(wov, idx, isf); }
  for (int idx=t; idx<2048; idx+=256){ wbuf[WB_SCS+idx]  = ldx(scs, idx, isf); }
  for (int idx=t; idx<1024; idx+=256){ wbuf[WB_SCV+idx]  = ldx(scv, idx, isf); }
}

__global__ void node_pre(const void* __restrict__ ns_g, const void* __restrict__ nv_g,
                         const float* __restrict__ wbuf, u16* __restrict__ sp16,
                         u16* __restrict__ vp16, const int* __restrict__ flag){
  int n = blockIdx.x*256 + threadIdx.x;
  if (n >= N_NODES) return;
  int isf = *flag;
  float a[16], b[48];
  #pragma unroll
  for (int u=0;u<16;u++) a[u] = ldx(ns_g, n*16+u, isf);
  #pragma unroll
  for (int u=0;u<48;u++) b[u] = ldx(nv_g, n*48+u, isf);

  const float* wins = wbuf + WB_WINS;
  const float* winv = wbuf + WB_WINV;
  float s[16];
  #pragma unroll
  for (int w=0;w<16;w++) s[w]=0.f;
  #pragma unroll
  for (int u=0;u<16;u++){
    float au = a[u];
    #pragma unroll
    for (int w=0;w<16;w++) s[w] += au * wins[u*16+w];
  }
  #pragma unroll
  for (int w=0;w<16;w++) sp16[n*16+w] = f2bf(s[w]);
  float v0[16], v1[16], v2[16];
  #pragma unroll
  for (int w=0;w<16;w++){ v0[w]=0.f; v1[w]=0.f; v2[w]=0.f; }
  #pragma unroll
  for (int u=0;u<16;u++){
    float bu0=b[u*3], bu1=b[u*3+1], bu2=b[u*3+2];
    #pragma unroll
    for (int w=0;w<16;w++){
      float wv = winv[u*16+w];
      v0[w] += bu0*wv; v1[w] += bu1*wv; v2[w] += bu2*wv;
    }
  }
  #pragma unroll
  for (int w=0;w<16;w++){
    vp16[n*48+w*3]   = f2bf(v0[w]);
    vp16[n*48+w*3+1] = f2bf(v1[w]);
    vp16[n*48+w*3+2] = f2bf(v2[w]);
  }
}

__global__ void count_edges(const int* __restrict__ receivers, int* __restrict__ deg){
  int e = blockIdx.x*256 + threadIdx.x;
  if (e < N_EDGES) atomicAdd(&deg[receivers[e]], 1);
}

__global__ void scan_offsets(const int* __restrict__ deg, int* __restrict__ offs,
                             int* __restrict__ curs){
  __shared__ int part[1024];
  int t = threadIdx.x;
  const int PER = 49;
  int base = t*PER;
  int s = 0;
  for (int i=0;i<PER;i++){ int n=base+i; if (n<N_NODES) s += deg[n]; }
  part[t] = s; __syncthreads();
  for (int off=1; off<1024; off<<=1){
    int v = (t>=off) ? part[t-off] : 0;
    __syncthreads(); part[t] += v; __syncthreads();
  }
  int run = (t==0) ? 0 : part[t-1];
  for (int i=0;i<PER;i++){
    int n=base+i;
    if (n<N_NODES){ offs[n]=run; curs[n]=run; run += deg[n]; }
  }
  if (t==1023) offs[N_NODES] = run;
}

// permute edge data into receiver-sorted order as packed 32B bf16 records
__global__ void fill_perm(const void* __restrict__ edge_sh, const void* __restrict__ remb,
                          const int* __restrict__ senders, const int* __restrict__ receivers,
                          int* __restrict__ curs, u32* __restrict__ perm,
                          const int* __restrict__ flag){
  int e = blockIdx.x*256 + threadIdx.x;
  if (e >= N_EDGES) return;
  int isf = *flag;
  float sh0 = ldx(edge_sh, (long long)e*4+0, isf);
  float sh1 = ldx(edge_sh, (long long)e*4+1, isf);
  float sh2 = ldx(edge_sh, (long long)e*4+2, isf);
  float sh3 = ldx(edge_sh, (long long)e*4+3, isf);
  float re[8];
  #pragma unroll
  for (int i=0;i<8;i++) re[i] = ldx(remb, (long long)e*8+i, isf);
  int snd = senders[e], rcv = receivers[e];
  int p = atomicAdd(&curs[rcv], 1);
  u32* rec = perm + (size_t)p*8;
  uint4 r0, r1;
  r0.x = pk2(sh0, sh1); r0.y = pk2(sh2, sh3);
  r0.z = pk2(re[0], re[1]); r0.w = pk2(re[2], re[3]);
  r1.x = pk2(re[4], re[5]); r1.y = pk2(re[6], re[7]);
  r1.z = (u32)snd; r1.w = (u32)rcv;
  *reinterpret_cast<uint4*>(rec)     = r0;
  *reinterpret_cast<uint4*>(rec + 4) = r1;
}

__global__ void __launch_bounds__(256) fused_gather(
    const u32* __restrict__ perm, const int* __restrict__ offs,
    const u16* __restrict__ sp16, const u16* __restrict__ vp16,
    const void* __restrict__ ns_g, const void* __restrict__ nv_g,
    const int* __restrict__ species, const float* __restrict__ wbuf,
    void* __restrict__ out, const int* __restrict__ flag){
  __shared__ float bins[RPB * BINW];   // 45.3 KB
  int tid = threadIdx.x;
  int r0 = blockIdx.x * RPB;
  int rEnd = min(r0 + RPB, N_NODES);
  int isf = *flag;

  for (int i = tid; i < RPB*BINW; i += 256) bins[i] = 0.f;
  __syncthreads();

  int beg = offs[r0], end = offs[rEnd];
  const float* w1t = wbuf + WB_W1T;
  const float* b1  = wbuf + WB_B1;
  const float* w2t = wbuf + WB_W2T;

  for (int idx = beg + tid; idx < end; idx += 256){
    const u32* rec = perm + (size_t)idx*8;
    uint4 q0 = *reinterpret_cast<const uint4*>(rec);
    uint4 q1 = *reinterpret_cast<const uint4*>(rec + 4);
    float Y0  = bf2f((u16)(q0.x&0xffffu)), Yv0 = bf2f((u16)(q0.x>>16));
    float Yv1 = bf2f((u16)(q0.y&0xffffu)), Yv2 = bf2f((u16)(q0.y>>16));
    float re[8];
    re[0]=bf2f((u16)(q0.z&0xffffu)); re[1]=bf2f((u16)(q0.z>>16));
    re[2]=bf2f((u16)(q0.w&0xffffu)); re[3]=bf2f((u16)(q0.w>>16));
    re[4]=bf2f((u16)(q1.x&0xffffu)); re[5]=bf2f((u16)(q1.x>>16));
    re[6]=bf2f((u16)(q1.y&0xffffu)); re[7]=bf2f((u16)(q1.y>>16));
    int snd = (int)q1.z;
    int bin = (int)q1.w - r0;
    float* bp = bins + bin*BINW;

    float h[64];
    #pragma unroll
    for (int j=0;j<64;j++){
      float acc = b1[j];
      #pragma unroll
      for (int i=0;i<8;i++) acc += re[i] * w1t[j*8+i];
      h[j] = acc * sigmoidf_(acc);
    }

    #pragma unroll
    for (int u0=0; u0<16; u0+=4){
      uint2 sq = *reinterpret_cast<const uint2*>(sp16 + (size_t)snd*16 + u0);
      float xs[4];
      xs[0]=bf2f((u16)(sq.x&0xffffu)); xs[1]=bf2f((u16)(sq.x>>16));
      xs[2]=bf2f((u16)(sq.y&0xffffu)); xs[3]=bf2f((u16)(sq.y>>16));
      const u16* vr = vp16 + (size_t)snd*48 + u0*3;
      uint2 a0 = *reinterpret_cast<const uint2*>(vr);
      uint2 a1 = *reinterpret_cast<const uint2*>(vr+4);
      uint2 a2 = *reinterpret_cast<const uint2*>(vr+8);
      float xv[12];
      xv[0]=bf2f((u16)(a0.x&0xffffu)); xv[1]=bf2f((u16)(a0.x>>16));
      xv[2]=bf2f((u16)(a0.y&0xffffu)); xv[3]=bf2f((u16)(a0.y>>16));
      xv[4]=bf2f((u16)(a1.x&0xffffu)); xv[5]=bf2f((u16)(a1.x>>16));
      xv[6]=bf2f((u16)(a1.y&0xffffu)); xv[7]=bf2f((u16)(a1.y>>16));
      xv[8]=bf2f((u16)(a2.x&0xffffu)); xv[9]=bf2f((u16)(a2.x>>16));
      xv[10]=bf2f((u16)(a2.y&0xffffu)); xv[11]=bf2f((u16)(a2.y>>16));
      #pragma unroll
      for (int k=0;k<4;k++){
        const float* wp = w2t + (u0+k)*64;   // wave-uniform -> s_load
        float w0=0.f,w1=0.f,w2=0.f,w3=0.f,w4=0.f;
        #pragma unroll
        for (int j=0;j<64;j++){
          float hj = h[j];
          w0 += hj*wp[j];
          w1 += hj*wp[1024+j];
          w2 += hj*wp[2048+j];
          w3 += hj*wp[3072+j];
          w4 += hj*wp[4096+j];
        }
        float xsk = xs[k];
        float x0 = xv[3*k], x1 = xv[3*k+1], x2 = xv[3*k+2];
        int u = u0 + k;
        atomicAdd(&bp[u],      w0 * xsk * Y0);
        atomicAdd(&bp[16+u],   w1 * (x0*Yv0 + x1*Yv1 + x2*Yv2));
        float t1 = w2 * xsk;
        atomicAdd(&bp[32 + 0*48 + 0*16 + u], t1*Yv0);
        atomicAdd(&bp[32 + 1*48 + 0*16 + u], t1*Yv1);
        atomicAdd(&bp[32 + 2*48 + 0*16 + u], t1*Yv2);
        float t2 = w3 * Y0;
        atomicAdd(&bp[32 + 0*48 + 1*16 + u], t2*x0);
        atomicAdd(&bp[32 + 1*48 + 1*16 + u], t2*x1);
        atomicAdd(&bp[32 + 2*48 + 1*16 + u], t2*x2);
        atomicAdd(&bp[32 + 0*48 + 2*16 + u], w4*(x1*Yv2 - x2*Yv1));
        atomicAdd(&bp[32 + 1*48 + 2*16 + u], w4*(x2*Yv0 - x0*Yv2));
        atomicAdd(&bp[32 + 2*48 + 2*16 + u], w4*(x0*Yv1 - x1*Yv0));
      }
    }
  }
  __syncthreads();

  // ---- fused node_post: stage 1 (scalar channel + gates) ----
  if (tid < RPB){
    int node = r0 + tid;
    if (node < N_NODES){
      float* bin = bins + tid*BINW;
      int sp = species[node];
      const float* wos = wbuf + WB_WOS;
      const float* scs = wbuf + WB_SCS + sp*512;
      float ns[16];
      #pragma unroll
      for (int u=0;u<16;u++) ns[u] = ldx(ns_g, (long long)node*16+u, isf);
      float ps[32];
      #pragma unroll
      for (int w=0;w<32;w++) ps[w]=0.f;
      #pragma unroll
      for (int u=0;u<32;u++){
        float au = bin[u]*0.25f;
        #pragma unroll
        for (int w=0;w<32;w++) ps[w] += au*wos[u*32+w];
      }
      #pragma unroll
      for (int u=0;u<16;u++){
        float nu = ns[u];
        #pragma unroll
        for (int w=0;w<32;w++) ps[w] += nu*scs[u*32+w];
      }
      if (isf){
        float* orow = (float*)out + (size_t)node*64;
        #pragma unroll
        for (int k=0;k<16;k++){ float x=ps[k]; orow[k] = x*sigmoidf_(x) + ns[k]; }
      } else {
        u16* orow = (u16*)out + (size_t)node*64;
        #pragma unroll
        for (int k=0;k<16;k++){ float x=ps[k]; orow[k] = f2bf(x*sigmoidf_(x) + ns[k]); }
      }
      #pragma unroll
      for (int k=0;k<16;k++) bin[k] = sigmoidf_(ps[16+k]);   // stash gates
    }
  }
  __syncthreads();

  // ---- stage 2: vector channels (node, c) ----
  if (tid < RPB*3){
    int ni = tid / 3, c = tid - ni*3;
    int node = r0 + ni;
    if (node < N_NODES){
      float* bin = bins + ni*BINW;
      int sp = species[node];
      const float* wov = wbuf + WB_WOV;
      const float* scv = wbuf + WB_SCV + sp*256;
      float vin[16];
      #pragma unroll
      for (int u=0;u<16;u++) vin[u] = ldx(nv_g, (long long)node*48 + u*3 + c, isf);
      float pv[16];
      #pragma unroll
      for (int w=0;w<16;w++) pv[w]=0.f;
      #pragma unroll
      for (int j=0;j<48;j++){
        float aj = bin[32 + c*48 + j]*0.25f;
        #pragma unroll
        for (int w=0;w<16;w++) pv[w] += aj*wov[j*16+w];
      }
      #pragma unroll
      for (int u=0;u<16;u++){
        float bu = vin[u];
        #pragma unroll
        for (int w=0;w<16;w++) pv[w] += bu*scv[u*16+w];
      }
      if (isf){
        float* orow = (float*)out + (size_t)node*64;
        #pragma unroll
        for (int w=0;w<16;w++) orow[16 + w*3 + c] = pv[w]*bin[w] + vin[w];
      } else {
        u16* orow = (u16*)out + (size_t)node*64;
        #pragma unroll
        for (int w=0;w<16;w++) orow[16 + w*3 + c] = f2bf(pv[w]*bin[w] + vin[w]);
      }
    }
  }
}

extern "C" void kernel_launch(void* const* d_in, const int* in_sizes, int n_in,
                              void* d_out, int out_size, void* d_ws, size_t ws_size,
                              hipStream_t stream){
  const void* node_scalars = d_in[0];
  const void* node_vectors = d_in[1];
  const void* edge_sh      = d_in[2];
  const void* radial_emb   = d_in[3];
  const int* senders      = (const int*)d_in[4];
  const int* receivers    = (const int*)d_in[5];
  const int* species      = (const int*)d_in[6];
  const void* W_in_s  = d_in[7];
  const void* W_in_v  = d_in[8];
  const void* mlp_w1  = d_in[9];
  const void* mlp_b1  = d_in[10];
  const void* mlp_w2  = d_in[11];
  const void* W_out_s = d_in[12];
  const void* W_out_v = d_in[13];
  const void* sc_s    = d_in[14];
  const void* sc_v    = d_in[15];

  float* wsf  = (float*)d_ws;
  int*   wsi  = (int*)d_ws;
  u32*   wsu  = (u32*)d_ws;
  float* wbuf = wsf + OFF_WBUF;
  u16*   sp16 = (u16*)(wsu + OFF_SP16);
  u16*   vp16 = (u16*)(wsu + OFF_VP16);
  int*   deg  = wsi + IDX_DEG;
  int*   offs = wsi + IDX_OFFS;
  int*   curs = wsi + IDX_CURS;
  u32*   perm = wsu + IDX_PERM;
  int*   flag = (int*)(wbuf + WB_FLAG);

  detect_dtype<<<1,1,0,stream>>>((const u32*)radial_emb, flag);
  hipMemsetAsync(deg, 0, (size_t)N_NODES*sizeof(int), stream);
  prep_weights<<<1,256,0,stream>>>(mlp_w1, mlp_b1, mlp_w2, W_in_s, W_in_v,
                                   W_out_s, W_out_v, sc_s, sc_v, wbuf, flag);
  node_pre<<<(N_NODES+255)/256,256,0,stream>>>(node_scalars, node_vectors, wbuf,
                                               sp16, vp16, flag);
  count_edges<<<(N_EDGES+255)/256,256,0,stream>>>(receivers, deg);
  scan_offsets<<<1,1024,0,stream>>>(deg, offs, curs);
  fill_perm<<<(N_EDGES+255)/256,256,0,stream>>>(edge_sh, radial_emb, senders, receivers,
                                                curs, perm, flag);
  fused_gather<<<(N_NODES+RPB-1)/RPB,256,0,stream>>>(perm, offs, sp16, vp16,
                                                     node_scalars, node_vectors, species,
                                                     wbuf, d_out, flag);
}